// Round 1
// baseline (1074.357 us; speedup 1.0000x reference)
//
#include <hip/hip_runtime.h>

// Problem constants (reference: E,D,H,N = 16,1024,4096,16384; uniform counts)
#define E_  16
#define D_  1024
#define H_  4096
#define NPE 1024  // tokens per expert = N/E

typedef __bf16 bf16x8 __attribute__((ext_vector_type(8)));
typedef float f32x4 __attribute__((ext_vector_type(4)));

__device__ __forceinline__ unsigned short f2bf(float f) {
  unsigned int u = __float_as_uint(f);
  u += 0x7fffu + ((u >> 16) & 1u);  // RNE
  return (unsigned short)(u >> 16);
}

// fp32 -> bf16 elementwise convert, float4-vectorized
__global__ __launch_bounds__(256) void cvt_f32_to_bf16(
    const float* __restrict__ in, unsigned short* __restrict__ out, int nvec) {
  int i = blockIdx.x * 256 + threadIdx.x;
  if (i >= nvec) return;
  float4 v = ((const float4*)in)[i];
  ushort4 o;
  o.x = f2bf(v.x);
  o.y = f2bf(v.y);
  o.z = f2bf(v.z);
  o.w = f2bf(v.w);
  ((ushort4*)out)[i] = o;
}

// Batched NT GEMM: C[e] = A[e] (MxK, row-major) * B[e]^T (B is NxK row-major)
//                  + bias[e] (per output col), optional ReLU + bf16 output.
// m97 structure: 128x128 block tile, BK=32, 256 threads = 4 waves (2x2),
// each wave 4x4 fragments of mfma_f32_16x16x32_bf16.
// LDS staged via global_load_lds width=16; K-chunk XOR swizzle (q ^ (row>>1)&3)
// to break ds_read_b128 bank conflicts (lane order in LDS is fixed by HW).
template <bool RELU_BF16_OUT>
__global__ __launch_bounds__(256) void gemm_bt(
    const unsigned short* __restrict__ A,   // [E][M][K] bf16
    const unsigned short* __restrict__ B,   // [E][N][K] bf16
    const float* __restrict__ bias,         // [E][N]
    void* __restrict__ Cout,                // [E][M][N] bf16 or f32
    int M, int N, int K) {
  __shared__ unsigned short ldsA[128 * 32];
  __shared__ unsigned short ldsB[128 * 32];

  const int tid  = threadIdx.x;
  const int lane = tid & 63;
  const int wave = tid >> 6;
  const int wm   = wave >> 1;
  const int wn   = wave & 1;
  const int fr   = lane & 15;  // fragment row/col within 16
  const int fq   = lane >> 4;  // quad 0..3

  const int e  = blockIdx.z;
  const int bm = blockIdx.y << 7;
  const int bn = blockIdx.x << 7;

  const unsigned short* Ae = A + (size_t)e * M * K;
  const unsigned short* Be = B + (size_t)e * N * K;

  // staging: thread tid covers tile row (tid>>2), 16B chunk (tid&3), x2 row-halves
  const int srow = tid >> 2;  // 0..63
  const int qp   = tid & 3;
  const int qg   = qp ^ ((srow >> 1) & 3);  // swizzled global chunk (same for row+64)

  const size_t arow0 = (size_t)(bm + srow) * K + qg * 8;
  const size_t arow1 = (size_t)(bm + srow + 64) * K + qg * 8;
  const size_t brow0 = (size_t)(bn + srow) * K + qg * 8;
  const size_t brow1 = (size_t)(bn + srow + 64) * K + qg * 8;
  unsigned short* lA0 = ldsA + wave * 512;         // HW adds lane*16B
  unsigned short* lA1 = ldsA + 2048 + wave * 512;
  unsigned short* lB0 = ldsB + wave * 512;
  unsigned short* lB1 = ldsB + 2048 + wave * 512;

  f32x4 acc[4][4];
  const f32x4 zero = {0.f, 0.f, 0.f, 0.f};
#pragma unroll
  for (int i = 0; i < 4; ++i)
#pragma unroll
    for (int j = 0; j < 4; ++j) acc[i][j] = zero;

  // LDS fragment read offsets (elements), same swizzle as staging
  int aoff[4], boff[4];
#pragma unroll
  for (int i = 0; i < 4; ++i) {
    int ra = wm * 64 + i * 16 + fr;
    aoff[i] = ra * 32 + ((fq ^ ((ra >> 1) & 3)) << 3);
    int rb = wn * 64 + i * 16 + fr;
    boff[i] = rb * 32 + ((fq ^ ((rb >> 1) & 3)) << 3);
  }

  const int kIters = K >> 5;
  for (int kt = 0; kt < kIters; ++kt) {
    const int k0 = kt << 5;
    __syncthreads();  // protect LDS from overwrite while prior iter reads in flight
    __builtin_amdgcn_global_load_lds((const unsigned int*)(Ae + arow0 + k0),
                                     (unsigned int*)lA0, 16, 0, 0);
    __builtin_amdgcn_global_load_lds((const unsigned int*)(Ae + arow1 + k0),
                                     (unsigned int*)lA1, 16, 0, 0);
    __builtin_amdgcn_global_load_lds((const unsigned int*)(Be + brow0 + k0),
                                     (unsigned int*)lB0, 16, 0, 0);
    __builtin_amdgcn_global_load_lds((const unsigned int*)(Be + brow1 + k0),
                                     (unsigned int*)lB1, 16, 0, 0);
    __syncthreads();  // drains vmcnt (global_load_lds) + lgkmcnt

    bf16x8 af[4], bfr[4];
#pragma unroll
    for (int i = 0; i < 4; ++i) af[i] = *(const bf16x8*)&ldsA[aoff[i]];
#pragma unroll
    for (int i = 0; i < 4; ++i) bfr[i] = *(const bf16x8*)&ldsB[boff[i]];

#pragma unroll
    for (int mi = 0; mi < 4; ++mi)
#pragma unroll
      for (int ni = 0; ni < 4; ++ni)
        acc[mi][ni] = __builtin_amdgcn_mfma_f32_16x16x32_bf16(af[mi], bfr[ni],
                                                              acc[mi][ni], 0, 0, 0);
  }

  // Epilogue. C/D layout: col = lane&15, row = (lane>>4)*4 + reg  [m89-verified]
  const int crow0 = bm + wm * 64 + fq * 4;
  const int ccol0 = bn + wn * 64 + fr;
  float bv[4];
#pragma unroll
  for (int ni = 0; ni < 4; ++ni) bv[ni] = bias[(size_t)e * N + ccol0 + ni * 16];

  if (RELU_BF16_OUT) {
    unsigned short* C = (unsigned short*)Cout + (size_t)e * M * N;
#pragma unroll
    for (int mi = 0; mi < 4; ++mi)
#pragma unroll
      for (int ni = 0; ni < 4; ++ni)
#pragma unroll
        for (int r = 0; r < 4; ++r) {
          float v = acc[mi][ni][r] + bv[ni];
          v = v > 0.f ? v : 0.f;
          C[(size_t)(crow0 + mi * 16 + r) * N + ccol0 + ni * 16] = f2bf(v);
        }
  } else {
    float* C = (float*)Cout + (size_t)e * M * N;
#pragma unroll
    for (int mi = 0; mi < 4; ++mi)
#pragma unroll
      for (int ni = 0; ni < 4; ++ni)
#pragma unroll
        for (int r = 0; r < 4; ++r) {
          C[(size_t)(crow0 + mi * 16 + r) * N + ccol0 + ni * 16] =
              acc[mi][ni][r] + bv[ni];
        }
  }
}

extern "C" void kernel_launch(void* const* d_in, const int* in_sizes, int n_in,
                              void* d_out, int out_size, void* d_ws, size_t ws_size,
                              hipStream_t stream) {
  (void)in_sizes; (void)n_in; (void)out_size; (void)ws_size;
  const float* xs = (const float*)d_in[0];
  // d_in[1] = fwd_expert_count: uniform N/E by construction (reference reshapes), unused
  const float* w1 = (const float*)d_in[2];
  const float* b1 = (const float*)d_in[3];
  const float* w2 = (const float*)d_in[4];
  const float* b2 = (const float*)d_in[5];
  float* y = (float*)d_out;

  // ws layout: xs_bf 32MB | w_bf 128MB (w1 then w2) | h_bf 128MB  => 288MB
  char* ws = (char*)d_ws;
  unsigned short* xs_bf = (unsigned short*)ws;
  unsigned short* w_bf  = (unsigned short*)(ws + (size_t)(32u << 20));
  unsigned short* h_bf  = (unsigned short*)(ws + (size_t)(160u << 20));

  const int nXs = E_ * NPE * D_;  // 16,777,216
  const int nW  = E_ * H_ * D_;   // 67,108,864

  cvt_f32_to_bf16<<<nXs / 4 / 256, 256, 0, stream>>>(xs, xs_bf, nXs / 4);
  cvt_f32_to_bf16<<<nW / 4 / 256, 256, 0, stream>>>(w1, w_bf, nW / 4);

  // GEMM1: h = relu(xs @ w1^T + b1), out bf16 [E][1024][4096]
  gemm_bt<true><<<dim3(H_ / 128, NPE / 128, E_), 256, 0, stream>>>(
      xs_bf, w_bf, b1, h_bf, NPE, H_, D_);

  cvt_f32_to_bf16<<<nW / 4 / 256, 256, 0, stream>>>(w2, w_bf, nW / 4);

  // GEMM2: y = h @ w2^T + b2, out f32 [E][1024][1024]
  gemm_bt<false><<<dim3(D_ / 128, NPE / 128, E_), 256, 0, stream>>>(
      h_bf, w_bf, b2, y, NPE, D_, H_);
}

// Round 2
// 1036.564 us; speedup vs baseline: 1.0365x; 1.0365x over previous
//
#include <hip/hip_runtime.h>

// Problem constants (reference: E,D,H,N = 16,1024,4096,16384; uniform counts)
#define E_  16
#define D_  1024
#define H_  4096
#define NPE 1024  // tokens per expert = N/E

typedef __bf16 bf16x8 __attribute__((ext_vector_type(8)));
typedef float f32x4 __attribute__((ext_vector_type(4)));

__device__ __forceinline__ unsigned short f2bf(float f) {
  unsigned int u = __float_as_uint(f);
  u += 0x7fffu + ((u >> 16) & 1u);  // RNE
  return (unsigned short)(u >> 16);
}

// fp32 -> bf16 elementwise convert, float4-vectorized
__global__ __launch_bounds__(256) void cvt_f32_to_bf16(
    const float* __restrict__ in, unsigned short* __restrict__ out, int nvec) {
  int i = blockIdx.x * 256 + threadIdx.x;
  if (i >= nvec) return;
  float4 v = ((const float4*)in)[i];
  ushort4 o;
  o.x = f2bf(v.x);
  o.y = f2bf(v.y);
  o.z = f2bf(v.z);
  o.w = f2bf(v.w);
  ((ushort4*)out)[i] = o;
}

// Batched NT GEMM: C[e] = A[e] (MxK, row-major) * B[e]^T (B is NxK row-major)
//                  + bias[e] (per output col), optional ReLU + bf16 output.
// 128x128 block tile, BK=32, 256 threads = 4 waves (2x2), 4x4 frags of
// mfma_f32_16x16x32_bf16 per wave. global_load_lds width=16 staging with
// K-chunk XOR swizzle (bank-conflict-free, R1: SQ_LDS_BANK_CONFLICT=0).
//
// R1 lesson: default (x,y,z) dispatch round-robins neighbors across XCDs ->
// L2 thrash, FETCH 790MB vs 160MB unique, MfmaUtil 18%. Fix: 1D grid with
// XCD-aware decode. region = id&7 (one per XCD under round-robin dispatch);
// each region owns E/8=2 experts; within an expert, tiles walk in Mt x SN
// supertiles (mt fastest) so the ~96 co-resident blocks of an XCD stream the
// SAME 4MB of A/B tiles at the same K-rate -> staging hits L2 (~200cyc).
template <bool RELU_BF16_OUT>
__global__ __launch_bounds__(256) void gemm_bt(
    const unsigned short* __restrict__ A,   // [E][M][K] bf16
    const unsigned short* __restrict__ B,   // [E][N][K] bf16
    const float* __restrict__ bias,         // [E][N]
    void* __restrict__ Cout,                // [E][M][N] bf16 or f32
    int M, int N, int K) {
  __shared__ unsigned short ldsA[128 * 32];
  __shared__ unsigned short ldsB[128 * 32];

  const int tid  = threadIdx.x;
  const int lane = tid & 63;
  const int wave = tid >> 6;
  const int wm   = wave >> 1;
  const int wn   = wave & 1;
  const int fr   = lane & 15;  // fragment row/col within 16
  const int fq   = lane >> 4;  // quad 0..3

  // ---- XCD-aware tile decode (1D grid: E * Mt * Nt blocks) ----
  const int Mt = M >> 7;
  const int Nt = N >> 7;
  const int id     = blockIdx.x;
  const int region = id & 7;       // heuristic: dispatch round-robins XCDs
  const int slot   = id >> 3;      // temporal order within the XCD
  const int bpe    = Mt * Nt;      // blocks per expert
  const int eloc   = slot / bpe;
  const int rem    = slot - eloc * bpe;
  const int e      = region * (E_ / 8) + eloc;
  const int SN     = Nt < 8 ? Nt : 8;
  const int csz    = Mt * SN;      // supertile size
  const int chunk  = rem / csz;
  const int inner  = rem - chunk * csz;
  const int mt     = inner % Mt;   // mt fastest within supertile
  const int nt     = chunk * SN + inner / Mt;

  const int bm = mt << 7;
  const int bn = nt << 7;

  const unsigned short* Ae = A + (size_t)e * M * K;
  const unsigned short* Be = B + (size_t)e * N * K;

  // staging: thread tid covers tile row (tid>>2), 16B chunk (tid&3), x2 row-halves
  const int srow = tid >> 2;  // 0..63
  const int qp   = tid & 3;
  const int qg   = qp ^ ((srow >> 1) & 3);  // swizzled global chunk (same for row+64)

  const size_t arow0 = (size_t)(bm + srow) * K + qg * 8;
  const size_t arow1 = (size_t)(bm + srow + 64) * K + qg * 8;
  const size_t brow0 = (size_t)(bn + srow) * K + qg * 8;
  const size_t brow1 = (size_t)(bn + srow + 64) * K + qg * 8;
  unsigned short* lA0 = ldsA + wave * 512;         // HW adds lane*16B
  unsigned short* lA1 = ldsA + 2048 + wave * 512;
  unsigned short* lB0 = ldsB + wave * 512;
  unsigned short* lB1 = ldsB + 2048 + wave * 512;

  f32x4 acc[4][4];
  const f32x4 zero = {0.f, 0.f, 0.f, 0.f};
#pragma unroll
  for (int i = 0; i < 4; ++i)
#pragma unroll
    for (int j = 0; j < 4; ++j) acc[i][j] = zero;

  // LDS fragment read offsets (elements), same swizzle as staging
  int aoff[4], boff[4];
#pragma unroll
  for (int i = 0; i < 4; ++i) {
    int ra = wm * 64 + i * 16 + fr;
    aoff[i] = ra * 32 + ((fq ^ ((ra >> 1) & 3)) << 3);
    int rb = wn * 64 + i * 16 + fr;
    boff[i] = rb * 32 + ((fq ^ ((rb >> 1) & 3)) << 3);
  }

  const int kIters = K >> 5;
  for (int kt = 0; kt < kIters; ++kt) {
    const int k0 = kt << 5;
    __syncthreads();  // protect LDS from overwrite while prior iter reads in flight
    __builtin_amdgcn_global_load_lds((const unsigned int*)(Ae + arow0 + k0),
                                     (unsigned int*)lA0, 16, 0, 0);
    __builtin_amdgcn_global_load_lds((const unsigned int*)(Ae + arow1 + k0),
                                     (unsigned int*)lA1, 16, 0, 0);
    __builtin_amdgcn_global_load_lds((const unsigned int*)(Be + brow0 + k0),
                                     (unsigned int*)lB0, 16, 0, 0);
    __builtin_amdgcn_global_load_lds((const unsigned int*)(Be + brow1 + k0),
                                     (unsigned int*)lB1, 16, 0, 0);
    __syncthreads();  // drains vmcnt (global_load_lds) + lgkmcnt

    bf16x8 af[4], bfr[4];
#pragma unroll
    for (int i = 0; i < 4; ++i) af[i] = *(const bf16x8*)&ldsA[aoff[i]];
#pragma unroll
    for (int i = 0; i < 4; ++i) bfr[i] = *(const bf16x8*)&ldsB[boff[i]];

#pragma unroll
    for (int mi = 0; mi < 4; ++mi)
#pragma unroll
      for (int ni = 0; ni < 4; ++ni)
        acc[mi][ni] = __builtin_amdgcn_mfma_f32_16x16x32_bf16(af[mi], bfr[ni],
                                                              acc[mi][ni], 0, 0, 0);
  }

  // Epilogue. C/D layout: col = lane&15, row = (lane>>4)*4 + reg  [m89-verified]
  const int crow0 = bm + wm * 64 + fq * 4;
  const int ccol0 = bn + wn * 64 + fr;
  float bv[4];
#pragma unroll
  for (int ni = 0; ni < 4; ++ni) bv[ni] = bias[(size_t)e * N + ccol0 + ni * 16];

  if (RELU_BF16_OUT) {
    unsigned short* C = (unsigned short*)Cout + (size_t)e * M * N;
#pragma unroll
    for (int mi = 0; mi < 4; ++mi)
#pragma unroll
      for (int ni = 0; ni < 4; ++ni)
#pragma unroll
        for (int r = 0; r < 4; ++r) {
          float v = acc[mi][ni][r] + bv[ni];
          v = v > 0.f ? v : 0.f;
          C[(size_t)(crow0 + mi * 16 + r) * N + ccol0 + ni * 16] = f2bf(v);
        }
  } else {
    float* C = (float*)Cout + (size_t)e * M * N;
#pragma unroll
    for (int mi = 0; mi < 4; ++mi)
#pragma unroll
      for (int ni = 0; ni < 4; ++ni)
#pragma unroll
        for (int r = 0; r < 4; ++r) {
          C[(size_t)(crow0 + mi * 16 + r) * N + ccol0 + ni * 16] =
              acc[mi][ni][r] + bv[ni];
        }
  }
}

extern "C" void kernel_launch(void* const* d_in, const int* in_sizes, int n_in,
                              void* d_out, int out_size, void* d_ws, size_t ws_size,
                              hipStream_t stream) {
  (void)in_sizes; (void)n_in; (void)out_size; (void)ws_size;
  const float* xs = (const float*)d_in[0];
  // d_in[1] = fwd_expert_count: uniform N/E by construction (reference reshapes), unused
  const float* w1 = (const float*)d_in[2];
  const float* b1 = (const float*)d_in[3];
  const float* w2 = (const float*)d_in[4];
  const float* b2 = (const float*)d_in[5];
  float* y = (float*)d_out;

  // ws layout: xs_bf 32MB | w_bf 128MB (w1 then w2) | h_bf 128MB  => 288MB
  char* ws = (char*)d_ws;
  unsigned short* xs_bf = (unsigned short*)ws;
  unsigned short* w_bf  = (unsigned short*)(ws + (size_t)(32u << 20));
  unsigned short* h_bf  = (unsigned short*)(ws + (size_t)(160u << 20));

  const int nXs = E_ * NPE * D_;  // 16,777,216
  const int nW  = E_ * H_ * D_;   // 67,108,864

  cvt_f32_to_bf16<<<nXs / 4 / 256, 256, 0, stream>>>(xs, xs_bf, nXs / 4);
  cvt_f32_to_bf16<<<nW / 4 / 256, 256, 0, stream>>>(w1, w_bf, nW / 4);

  // GEMM1: h = relu(xs @ w1^T + b1), out bf16 [E][1024][4096]
  gemm_bt<true><<<E_ * (NPE / 128) * (H_ / 128), 256, 0, stream>>>(
      xs_bf, w_bf, b1, h_bf, NPE, H_, D_);

  cvt_f32_to_bf16<<<nW / 4 / 256, 256, 0, stream>>>(w2, w_bf, nW / 4);

  // GEMM2: y = h @ w2^T + b2, out f32 [E][1024][1024]
  gemm_bt<false><<<E_ * (NPE / 128) * (D_ / 128), 256, 0, stream>>>(
      h_bf, w_bf, b2, y, NPE, D_, H_);
}